// Round 6
// baseline (631.174 us; speedup 1.0000x reference)
//
#include <hip/hip_runtime.h>
#include <hip/hip_bf16.h>

#define Bb 8
#define Tt 2048
#define Dd 512
#define Ss 4
#define GHh 64
#define NCHUNK 64
#define CH 32

typedef __hip_bfloat16 bf16;
typedef short bf16x8 __attribute__((ext_vector_type(8)));
typedef short bf16x4 __attribute__((ext_vector_type(4)));
typedef float f32x4 __attribute__((ext_vector_type(4)));
__device__ __forceinline__ float b2f(bf16 x){ return __bfloat162float(x); }
__device__ __forceinline__ float b2fs(short x){ bf16 t; __builtin_memcpy(&t,&x,2); return __bfloat162float(t); }

#define GLOAD_LDS16(g, l) \
  __builtin_amdgcn_global_load_lds((const __attribute__((address_space(1))) unsigned int*)(const void*)(g), \
                                   (__attribute__((address_space(3))) unsigned int*)(l), 16, 0, 0)

// ---------------- K0a: h f32 -> bf16 ----------------
__global__ __launch_bounds__(256) void k0a_cvt(const float* __restrict__ h, bf16* __restrict__ hb){
  int i = (blockIdx.x*256 + threadIdx.x)*4;
  float4 v = *reinterpret_cast<const float4*>(&h[i]);
  hb[i+0] = __float2bfloat16(v.x);
  hb[i+1] = __float2bfloat16(v.y);
  hb[i+2] = __float2bfloat16(v.z);
  hb[i+3] = __float2bfloat16(v.w);
}

// ---------------- K0b: pack+transpose weights -> Wt[4352][512] bf16 ----------------
__global__ __launch_bounds__(256) void k0b_pack(const float* __restrict__ predW,
    const float* __restrict__ writeW, const float* __restrict__ gateW1, bf16* __restrict__ Wt){
  __shared__ float tile[32][33];
  int k0 = blockIdx.x*32, n0 = blockIdx.y*32;
  int tx = threadIdx.x & 31, ty = threadIdx.x >> 5;   // 32 x 8
  #pragma unroll
  for (int p = 0; p < 4; ++p) {
    int kk = ty + p*8;
    int n = n0 + tx, k = k0 + kk;
    float v;
    if (n < 2048)      { int s=n>>9, o=n&511;              v = predW[((size_t)s*512+k)*512+o]; }
    else if (n < 4096) { int n2=n-2048; int s=n2>>9,o=n2&511; v = writeW[((size_t)s*512+k)*512+o]; }
    else               { int n2=n-4096; int s=n2>>6,hh=n2&63; v = gateW1[((size_t)s*521+k)*64+hh]; }
    tile[kk][tx] = v;
  }
  __syncthreads();
  #pragma unroll
  for (int p = 0; p < 4; ++p) {
    int nn = ty + p*8;
    Wt[(size_t)(n0+nn)*512 + k0 + tx] = __float2bfloat16(tile[tx][nn]);
  }
}

// ---------------- K1: MFMA GEMM  M=16384, K=512, N=4352 (B^T layout) ----------------
// 256x256 tile (halves global->LDS staging volume vs 128x128), BK=64, 512 threads,
// 8 waves as 2M x 4N (wave tile 128x64, acc[8][4]). Double-buffered LDS (128 KB),
// XOR-swizzled rows (128 B row = 8 x 16 B slots, slot q at row r holds q^(r&7)),
// stage(t+1) before compute(t), one barrier per K-step. Linear dispatch, n-fastest.
__global__ __launch_bounds__(512) void k1_mfma(
    const bf16* __restrict__ hb, const bf16* __restrict__ Wt,
    const float* __restrict__ h, const float* __restrict__ predb, const float* __restrict__ writeb,
    bf16* __restrict__ wenc, float* __restrict__ hg, float* __restrict__ errsq)
{
  __shared__ bf16 As[2][256*64];
  __shared__ bf16 Bs[2][256*64];
  const int tid = threadIdx.x;
  const int w = tid >> 6, lane = tid & 63;
  const int n0 = blockIdx.x * 256;     // 0..16
  const int row0 = blockIdx.y * 256;   // 0..63
  const int wm = w & 1, wn = w >> 1;   // 2M x 4N waves of 128x64
  const int mrow = lane & 15, kq = lane >> 4;

  f32x4 acc[8][4];
  #pragma unroll
  for (int i=0;i<8;++i)
    #pragma unroll
    for (int j=0;j<4;++j) acc[i][j] = (f32x4){0.f,0.f,0.f,0.f};

  // staging: wave w covers tile rows [w*32, w*32+32); each inst = 8 rows (64 lanes x 16 B)
  // LDS dest linear (base + lane*16); global source slot inverse-swizzled.
  const int srow  = lane >> 3;                 // row within 8-row group == (tile_row & 7)
  const int sslot = (lane & 7) ^ srow;         // swizzled source slot
  const bf16* gaBase = hb + (size_t)(row0 + w*32 + srow)*512 + sslot*8;
  const bf16* gbBase = Wt + (size_t)(n0  + w*32 + srow)*512 + sslot*8;

  auto STAGE = [&](int buf, int kstep){
    const bf16* ga = gaBase + kstep*64;
    const bf16* gb = gbBase + kstep*64;
    bf16* lA = &As[buf][(w*32)*64];
    bf16* lB = &Bs[buf][(w*32)*64];
    #pragma unroll
    for (int i=0;i<4;++i) {
      GLOAD_LDS16(ga + (size_t)i*8*512, lA + i*8*64);
      GLOAD_LDS16(gb + (size_t)i*8*512, lB + i*8*64);
    }
  };

  auto COMPUTE = [&](int buf){
    #pragma unroll
    for (int kk=0; kk<2; ++kk) {
      bf16x8 bfr[4];
      #pragma unroll
      for (int ni=0;ni<4;++ni) {
        int r = wn*64 + ni*16 + mrow;
        bfr[ni] = *reinterpret_cast<const bf16x8*>(&Bs[buf][r*64 + (((kk*4+kq) ^ (r&7))<<3)]);
      }
      #pragma unroll
      for (int mi=0;mi<8;++mi) {
        int r = wm*128 + mi*16 + mrow;
        bf16x8 af = *reinterpret_cast<const bf16x8*>(&As[buf][r*64 + (((kk*4+kq) ^ (r&7))<<3)]);
        #pragma unroll
        for (int ni=0;ni<4;++ni)
          acc[mi][ni] = __builtin_amdgcn_mfma_f32_16x16x32_bf16(af, bfr[ni], acc[mi][ni], 0, 0, 0);
      }
    }
  };

  STAGE(0, 0);
  __syncthreads();                 // drains vmcnt(0): buf0 ready
  #pragma unroll
  for (int t = 0; t < 8; ++t) {
    if (t < 7) STAGE((t+1)&1, t+1);  // next-tile loads in flight during compute
    COMPUTE(t&1);
    __syncthreads();
  }

  // epilogue: D element (mi,ni,reg) -> row = row0+wm*128+mi*16+kq*4+reg, col = n0+wn*64+ni*16+mrow
  if (n0 < 2048) {
    const int s = n0 >> 9;
    #pragma unroll
    for (int mi=0;mi<8;++mi) {
      #pragma unroll
      for (int reg=0;reg<4;++reg) {
        int r = row0 + wm*128 + mi*16 + kq*4 + reg;
        float sum = 0.f;
        if ((r & 2047) != 2047) {
          #pragma unroll
          for (int ni=0;ni<4;++ni) {
            int o = (n0 & 511) + wn*64 + ni*16 + mrow;
            float P = acc[mi][ni][reg] + predb[s*512 + o];
            float d = P - h[(size_t)(r+1)*512 + o];
            sum = fmaf(d, d, sum);
          }
        }
        #pragma unroll
        for (int off=1; off<16; off<<=1) sum += __shfl_xor(sum, off);
        if (mrow == 0 && (r & 2047) != 2047)
          atomicAdd(&errsq[(size_t)(r+1)*4 + s], sum);
      }
    }
  } else if (n0 < 4096) {
    #pragma unroll
    for (int mi=0;mi<8;++mi)
      #pragma unroll
      for (int ni=0;ni<4;++ni) {
        int n2 = n0 - 2048 + wn*64 + ni*16 + mrow;
        int s = n2 >> 9, o = n2 & 511;
        float wb = writeb[s*512 + o];
        #pragma unroll
        for (int reg=0;reg<4;++reg) {
          int r = row0 + wm*128 + mi*16 + kq*4 + reg;
          wenc[((size_t)r*4 + s)*512 + o] = __float2bfloat16(acc[mi][ni][reg] + wb);
        }
      }
  } else {
    #pragma unroll
    for (int mi=0;mi<8;++mi)
      #pragma unroll
      for (int ni=0;ni<4;++ni) {
        int n2 = wn*64 + ni*16 + mrow;
        int s = n2 >> 6, hh = n2 & 63;
        #pragma unroll
        for (int reg=0;reg<4;++reg) {
          int r = row0 + wm*128 + mi*16 + kq*4 + reg;
          hg[((size_t)r*4 + s)*64 + hh] = acc[mi][ni][reg];
        }
      }
  }
}

// ---------------- K2: fused err/em/MU/sd/SIG/base1 (single block) ----------------
// Phase A: err = sqrt(errsq+1e-8) (0 at t==0), em = mean_b -> LDS
// Phase B: MU = EMA-scan(em) (chunked-parallel), kept in LDS + written out
// Phase C: sd = mean_b |err - MU| -> LDS
// Phase D: SIG = EMA-scan(sd), init 1
// Phase E: base1
__global__ __launch_bounds__(256) void k2_fused(const float* __restrict__ errsq,
    const float* __restrict__ gateW1, const float* __restrict__ semb, const float* __restrict__ gateb1,
    float* __restrict__ err, float* __restrict__ MU, float* __restrict__ SIG, float* __restrict__ base1){
  __shared__ float s_em[8192];
  __shared__ float s_mu[8192];
  __shared__ float sA[256], sB[256], s_entry[256];
  const int tid = threadIdx.x;
  // Phase A
  for (int i = tid; i < 8192; i += 256) {
    int t = i >> 2;
    float sum = 0.f;
    #pragma unroll
    for (int b=0;b<8;++b){
      float e = (t > 0) ? sqrtf(errsq[b*8192 + i] + 1e-8f) : 0.f;
      err[b*8192 + i] = e;
      sum += e;
    }
    s_em[i] = sum * 0.125f;
  }
  __syncthreads();
  // Phase B: MU scan
  {
    const int c = tid >> 2, s = tid & 3;
    float A = 1.f, Bv = 0.f;
    #pragma unroll 8
    for (int i2 = 0; i2 < 32; ++i2) {
      int t = c*32 + i2;
      if (t >= 1) { A *= 0.99f; Bv = fmaf(0.99f, Bv, 0.01f * s_em[t*4 + s]); }
    }
    sA[tid] = A; sB[tid] = Bv;
    __syncthreads();
    if (tid < 4) {
      float v = 0.f;
      for (int cc = 0; cc < 64; ++cc) { s_entry[cc*4 + tid] = v; v = fmaf(sA[cc*4 + tid], v, sB[cc*4 + tid]); }
    }
    __syncthreads();
    float v = s_entry[tid];
    #pragma unroll 8
    for (int i2 = 0; i2 < 32; ++i2) {
      int t = c*32 + i2;
      s_mu[t*4 + s] = v; MU[t*4 + s] = v;
      if (t >= 1) v = fmaf(0.99f, v, 0.01f * s_em[t*4 + s]);
    }
  }
  __syncthreads();
  // Phase C: sd (err re-read by the same thread that wrote it; mu via LDS)
  for (int i = tid; i < 8192; i += 256) {
    float mu = s_mu[i];
    float sum = 0.f;
    #pragma unroll
    for (int b=0;b<8;++b) sum += fabsf(err[b*8192 + i] - mu);
    s_em[i] = sum * 0.125f;   // reuse em buffer for sd
  }
  __syncthreads();
  // Phase D: SIG scan (init 1)
  {
    const int c = tid >> 2, s = tid & 3;
    float A = 1.f, Bv = 0.f;
    #pragma unroll 8
    for (int i2 = 0; i2 < 32; ++i2) {
      int t = c*32 + i2;
      if (t >= 1) { A *= 0.99f; Bv = fmaf(0.99f, Bv, 0.01f * s_em[t*4 + s]); }
    }
    sA[tid] = A; sB[tid] = Bv;
    __syncthreads();
    if (tid < 4) {
      float v = 1.f;
      for (int cc = 0; cc < 64; ++cc) { s_entry[cc*4 + tid] = v; v = fmaf(sA[cc*4 + tid], v, sB[cc*4 + tid]); }
    }
    __syncthreads();
    float v = s_entry[tid];
    #pragma unroll 8
    for (int i2 = 0; i2 < 32; ++i2) {
      int t = c*32 + i2;
      SIG[t*4 + s] = v;
      if (t >= 1) v = fmaf(0.99f, v, 0.01f * s_em[t*4 + s]);
    }
  }
  // Phase E: base1 (independent of phases A-D)
  for (int i = tid; i < 768; i += 256) {
    int hh = i & 63, k = (i >> 6) % 3, s = i / 192;
    float acc = gateb1[s*64 + hh];
    #pragma unroll
    for (int e = 0; e < 8; ++e)
      acc = fmaf(semb[k*8+e], gateW1[((size_t)s*521 + 513 + e)*64 + hh], acc);
    base1[i] = acc;
  }
}

// ---------------- K3: g_all[b,t,s,k] (float4 inner loop) ----------------
__global__ void k3_gall(const float* __restrict__ hg, const float* __restrict__ err,
    const float* __restrict__ MU, const float* __restrict__ SIG,
    const float* __restrict__ gateW1, const float* __restrict__ base1,
    const float* __restrict__ gateW2, const float* __restrict__ gateb2,
    float* __restrict__ g_all)
{
  int i = blockIdx.x*256 + threadIdx.x;   // bts*3 + k
  int k = i % 3;
  int bts = i / 3;
  int s = bts & 3;
  int t = (bts >> 2) & 2047;
  float e = err[bts];
  float z = (e - MU[t*4+s]) / fmaxf(SIG[t*4+s], 1e-3f);
  const float4* hgp  = reinterpret_cast<const float4*>(&hg[(size_t)bts*64]);
  const float4* b1p  = reinterpret_cast<const float4*>(&base1[(s*3 + k)*64]);
  const float4* w1zp = reinterpret_cast<const float4*>(&gateW1[((size_t)s*521 + 512)*64]);
  const float4* w2p  = reinterpret_cast<const float4*>(&gateW2[s*64]);
  float logit = 0.f;
  #pragma unroll
  for (int hq = 0; hq < 16; ++hq) {
    float4 hv = hgp[hq], bv = b1p[hq], wz = w1zp[hq], w2 = w2p[hq];
    logit = fmaf(fmaxf(fmaf(z, wz.x, hv.x) + bv.x, 0.f), w2.x, logit);
    logit = fmaf(fmaxf(fmaf(z, wz.y, hv.y) + bv.y, 0.f), w2.y, logit);
    logit = fmaf(fmaxf(fmaf(z, wz.z, hv.z) + bv.z, 0.f), w2.z, logit);
    logit = fmaf(fmaxf(fmaf(z, wz.w, hv.w) + bv.w, 0.f), w2.w, logit);
  }
  logit += gateb2[s];
  g_all[i] = 1.f/(1.f + expf(-logit));
}

// ---------------- K3b: gm[t,s,k] = mean_b g_all ----------------
__global__ void k3b_gm(const float* __restrict__ g_all, float* __restrict__ gm){
  int i = blockIdx.x*256 + threadIdx.x;
  float sum = 0.f;
  #pragma unroll
  for (int b=0;b<8;++b) sum += g_all[((size_t)b*8192 + i/3)*3 + (i%3)];
  gm[i] = sum * 0.125f;
}

// ---------------- K4: state-machine scalar scan (latency-optimized) ----------------
__global__ __launch_bounds__(256) void k4_scan(const float* __restrict__ gm, int* __restrict__ states){
  __shared__ float s_gm[2][6144];
  for (int i = threadIdx.x; i < 6144; i += 256) s_gm[0][i] = gm[i];
  __syncthreads();
  float ema = 0.5f; int st = 0;
  for (int c = 0; c < 4; ++c) {
    if (c < 3)
      for (int i = threadIdx.x; i < 6144; i += 256) s_gm[(c+1)&1][i] = gm[(c+1)*6144 + i];
    if (threadIdx.x < 4) {
      int s = threadIdx.x;
      const float* gp = &s_gm[c&1][s*3];
      int* sp = &states[c*2048 + s];   // states[(c*512+tt)*4+s]
      #pragma unroll 8
      for (int tt = 0; tt < 512; ++tt) {
        sp[tt*4] = st;
        float g0 = gp[tt*12+0], g1 = gp[tt*12+1], g2 = gp[tt*12+2];
        float base = 0.99f * ema;
        float e0 = fmaf(0.01f, g0, base);
        float e1 = fmaf(0.01f, g1, base);
        float e2 = fmaf(0.01f, g2, base);
        ema = (st == 0) ? e0 : ((st == 1) ? e1 : e2);
        int n0 = (ema < 0.1f) ? 1 : 0;
        int n1 = (ema < 0.03f) ? 2 : ((ema > 0.25f) ? 0 : 1);
        int n2 = (ema > 0.25f) ? 0 : 2;
        st = (st == 0) ? n0 : ((st == 1) ? n1 : n2);
      }
    }
    __syncthreads();
  }
}

// ---------------- K5: a[b,t,s] = g_all[...,state] * gain[state] ----------------
__global__ void k5_a(const float* __restrict__ g_all, const int* __restrict__ states, float* __restrict__ a){
  int i = blockIdx.x*256 + threadIdx.x;
  int ts = i & 8191;
  int st = states[ts];
  float gain = (st == 0) ? 1.f : ((st == 1) ? 0.5f : 0.1f);
  a[i] = g_all[(size_t)i*3 + st] * gain;
}

// ---------------- K6: pass-1 chunk recurrence (4+4 dims/thread, fully coalesced) ----------------
__global__ __launch_bounds__(64) void k6_pass1(const float* __restrict__ a, const bf16* __restrict__ wenc,
      float* __restrict__ q, float* __restrict__ Pc){
  int c = blockIdx.x, s = blockIdx.y, b = blockIdx.z;
  int d0 = threadIdx.x * 4;          // dims [d0,d0+4) and [256+d0, 256+d0+4)
  __shared__ float s_a[CH];
  if (threadIdx.x < CH) s_a[threadIdx.x] = a[(size_t)(b*2048 + c*CH + threadIdx.x)*4 + s];
  __syncthreads();
  float qv[8];
  #pragma unroll
  for (int j=0;j<8;++j) qv[j] = 0.f;
  float p = 1.f;
  const bf16* wp = &wenc[((size_t)(b*2048 + c*CH)*4 + s)*512];
  #pragma unroll 4
  for (int i = 0; i < CH; ++i) {
    float av = s_a[i];
    float om = 1.f - av;
    bf16x4 w1 = *reinterpret_cast<const bf16x4*>(wp + (size_t)i*2048 + d0);
    bf16x4 w2 = *reinterpret_cast<const bf16x4*>(wp + (size_t)i*2048 + 256 + d0);
    #pragma unroll
    for (int j=0;j<4;++j) qv[j]   = fmaf(om, qv[j],   av*b2fs(w1[j]));
    #pragma unroll
    for (int j=0;j<4;++j) qv[4+j] = fmaf(om, qv[4+j], av*b2fs(w2[j]));
    p *= om;
  }
  float* qp = &q[((size_t)(b*4+s)*NCHUNK + c)*512];
  *reinterpret_cast<float4*>(qp + d0)       = make_float4(qv[0],qv[1],qv[2],qv[3]);
  *reinterpret_cast<float4*>(qp + 256 + d0) = make_float4(qv[4],qv[5],qv[6],qv[7]);
  if (threadIdx.x == 0) Pc[(b*4+s)*NCHUNK + c] = p;
}

// ---------------- K7: boundary scan (float4) ----------------
__global__ __launch_bounds__(128) void k7_bound(const float* __restrict__ q, const float* __restrict__ Pc,
      const float* __restrict__ w0, float* __restrict__ m_start){
  int s = blockIdx.x, b = blockIdx.y, d4 = threadIdx.x * 4;
  float4 m = *reinterpret_cast<const float4*>(&w0[s*512 + d4]);
  for (int c = 0; c < NCHUNK; ++c) {
    *reinterpret_cast<float4*>(&m_start[((size_t)(b*4+s)*NCHUNK + c)*512 + d4]) = m;
    float pc = Pc[(b*4+s)*NCHUNK + c];
    float4 qv = *reinterpret_cast<const float4*>(&q[((size_t)(b*4+s)*NCHUNK + c)*512 + d4]);
    m.x = fmaf(pc, m.x, qv.x);
    m.y = fmaf(pc, m.y, qv.y);
    m.z = fmaf(pc, m.z, qv.z);
    m.w = fmaf(pc, m.w, qv.w);
  }
}

// ---------------- K8: pass-2 emit (4+4 dims/thread, fully coalesced) ----------------
__global__ __launch_bounds__(64) void k8_pass2(const float* __restrict__ a, const bf16* __restrict__ wenc,
      const float* __restrict__ m_start, float* __restrict__ out){
  int c = blockIdx.x, s = blockIdx.y, b = blockIdx.z;
  int d0 = threadIdx.x * 4;
  __shared__ float s_a[CH];
  if (threadIdx.x < CH) s_a[threadIdx.x] = a[(size_t)(b*2048 + c*CH + threadIdx.x)*4 + s];
  __syncthreads();
  const float* msp = &m_start[((size_t)(b*4+s)*NCHUNK + c)*512];
  float4 m1 = *reinterpret_cast<const float4*>(msp + d0);
  float4 m2 = *reinterpret_cast<const float4*>(msp + 256 + d0);
  const bf16* wp = &wenc[((size_t)(b*2048 + c*CH)*4 + s)*512];
  float* op = &out[((size_t)(b*2048 + c*CH))*2048 + s*512];
  #pragma unroll 2
  for (int i = 0; i < CH; ++i) {
    float av = s_a[i];
    float om = 1.f - av;
    bf16x4 w1 = *reinterpret_cast<const bf16x4*>(wp + (size_t)i*2048 + d0);
    bf16x4 w2 = *reinterpret_cast<const bf16x4*>(wp + (size_t)i*2048 + 256 + d0);
    m1.x = fmaf(om, m1.x, av*b2fs(w1[0]));
    m1.y = fmaf(om, m1.y, av*b2fs(w1[1]));
    m1.z = fmaf(om, m1.z, av*b2fs(w1[2]));
    m1.w = fmaf(om, m1.w, av*b2fs(w1[3]));
    m2.x = fmaf(om, m2.x, av*b2fs(w2[0]));
    m2.y = fmaf(om, m2.y, av*b2fs(w2[1]));
    m2.z = fmaf(om, m2.z, av*b2fs(w2[2]));
    m2.w = fmaf(om, m2.w, av*b2fs(w2[3]));
    *reinterpret_cast<float4*>(op + (size_t)i*2048 + d0)       = m1;
    *reinterpret_cast<float4*>(op + (size_t)i*2048 + 256 + d0) = m2;
  }
}

extern "C" void kernel_launch(void* const* d_in, const int* in_sizes, int n_in,
                              void* d_out, int out_size, void* d_ws, size_t ws_size,
                              hipStream_t stream) {
  (void)in_sizes; (void)n_in; (void)out_size; (void)ws_size;
  const float* h      = (const float*)d_in[0];
  const float* predW  = (const float*)d_in[1];
  const float* predb  = (const float*)d_in[2];
  const float* gateW1 = (const float*)d_in[3];
  const float* gateb1 = (const float*)d_in[4];
  const float* gateW2 = (const float*)d_in[5];
  const float* gateb2 = (const float*)d_in[6];
  const float* writeW = (const float*)d_in[7];
  const float* writeb = (const float*)d_in[8];
  const float* w0     = (const float*)d_in[9];
  const float* semb   = (const float*)d_in[10];
  float* out = (float*)d_out;

  char* ws = (char*)d_ws;
  size_t off = 0;
  auto alloc = [&](size_t bytes) -> char* {
    char* p = ws + off; off += (bytes + 255) / 256 * 256; return p;
  };
  bf16*  wenc   = (bf16*) alloc((size_t)Bb*Tt*Ss*Dd*2);      // 67 MB
  float* hg     = (float*)alloc((size_t)Bb*Tt*Ss*GHh*4);     // 16.8 MB
  bf16*  hb     = (bf16*) alloc((size_t)Bb*Tt*Dd*2);         // 16.8 MB
  bf16*  Wt     = (bf16*) alloc((size_t)4352*512*2);         // 4.5 MB
  float* errsq  = (float*)alloc((size_t)Bb*Tt*Ss*4);
  float* err    = (float*)alloc((size_t)Bb*Tt*Ss*4);
  float* MU     = (float*)alloc((size_t)Tt*Ss*4);
  float* SIG    = (float*)alloc((size_t)Tt*Ss*4);
  float* base1  = (float*)alloc((size_t)Ss*3*GHh*4);
  float* g_all  = (float*)alloc((size_t)Bb*Tt*Ss*3*4);       // 3 MB
  float* gm     = (float*)alloc((size_t)Tt*Ss*3*4);
  int*   states = (int*)  alloc((size_t)Tt*Ss*4);
  float* av     = (float*)alloc((size_t)Bb*Tt*Ss*4);
  float* Pc     = (float*)alloc((size_t)Bb*Ss*NCHUNK*4);
  float* q      = (float*)alloc((size_t)Bb*Ss*NCHUNK*Dd*4);  // 4 MB
  float* mst    = (float*)alloc((size_t)Bb*Ss*NCHUNK*Dd*4);  // 4 MB

  hipMemsetAsync(errsq, 0, (size_t)Bb*Tt*Ss*4, stream);

  k0a_cvt<<<(Bb*Tt*Dd)/(256*4), 256, 0, stream>>>(h, hb);
  dim3 g0b(16, 136);
  k0b_pack<<<g0b, 256, 0, stream>>>(predW, writeW, gateW1, Wt);
  dim3 g1(17, 64);
  k1_mfma<<<g1, 512, 0, stream>>>(hb, Wt, h, predb, writeb, wenc, hg, errsq);
  k2_fused<<<1, 256, 0, stream>>>(errsq, gateW1, semb, gateb1, err, MU, SIG, base1);
  k3_gall<<<(Bb*Tt*Ss*3)/256, 256, 0, stream>>>(hg, err, MU, SIG, gateW1, base1, gateW2, gateb2, g_all);
  k3b_gm<<<(Tt*Ss*3)/256, 256, 0, stream>>>(g_all, gm);
  k4_scan<<<1, 256, 0, stream>>>(gm, states);
  k5_a<<<(Bb*Tt*Ss)/256, 256, 0, stream>>>(g_all, states, av);
  dim3 g6(NCHUNK, Ss, Bb);
  k6_pass1<<<g6, 64, 0, stream>>>(av, wenc, q, Pc);
  dim3 g7(Ss, Bb);
  k7_bound<<<g7, 128, 0, stream>>>(q, Pc, w0, mst);
  k8_pass2<<<g6, 64, 0, stream>>>(av, wenc, mst, out);
}

// Round 7
// 542.114 us; speedup vs baseline: 1.1643x; 1.1643x over previous
//
#include <hip/hip_runtime.h>
#include <hip/hip_bf16.h>

#define Bb 8
#define Tt 2048
#define Dd 512
#define Ss 4
#define GHh 64
#define NCHUNK 64
#define CH 32

typedef __hip_bfloat16 bf16;
typedef short bf16x8 __attribute__((ext_vector_type(8)));
typedef short bf16x4 __attribute__((ext_vector_type(4)));
typedef float f32x4 __attribute__((ext_vector_type(4)));
__device__ __forceinline__ float b2f(bf16 x){ return __bfloat162float(x); }
__device__ __forceinline__ float b2fs(short x){ bf16 t; __builtin_memcpy(&t,&x,2); return __bfloat162float(t); }

#define GLOAD_LDS16(g, l) \
  __builtin_amdgcn_global_load_lds((const __attribute__((address_space(1))) unsigned int*)(const void*)(g), \
                                   (__attribute__((address_space(3))) unsigned int*)(l), 16, 0, 0)

// ---------------- K0a: h f32 -> bf16 ----------------
__global__ __launch_bounds__(256) void k0a_cvt(const float* __restrict__ h, bf16* __restrict__ hb){
  int i = (blockIdx.x*256 + threadIdx.x)*4;
  float4 v = *reinterpret_cast<const float4*>(&h[i]);
  hb[i+0] = __float2bfloat16(v.x);
  hb[i+1] = __float2bfloat16(v.y);
  hb[i+2] = __float2bfloat16(v.z);
  hb[i+3] = __float2bfloat16(v.w);
}

// ---------------- K0b: pack+transpose weights -> Wt[4352][512] bf16 ----------------
__global__ __launch_bounds__(256) void k0b_pack(const float* __restrict__ predW,
    const float* __restrict__ writeW, const float* __restrict__ gateW1, bf16* __restrict__ Wt){
  __shared__ float tile[32][33];
  int k0 = blockIdx.x*32, n0 = blockIdx.y*32;
  int tx = threadIdx.x & 31, ty = threadIdx.x >> 5;   // 32 x 8
  #pragma unroll
  for (int p = 0; p < 4; ++p) {
    int kk = ty + p*8;
    int n = n0 + tx, k = k0 + kk;
    float v;
    if (n < 2048)      { int s=n>>9, o=n&511;              v = predW[((size_t)s*512+k)*512+o]; }
    else if (n < 4096) { int n2=n-2048; int s=n2>>9,o=n2&511; v = writeW[((size_t)s*512+k)*512+o]; }
    else               { int n2=n-4096; int s=n2>>6,hh=n2&63; v = gateW1[((size_t)s*521+k)*64+hh]; }
    tile[kk][tx] = v;
  }
  __syncthreads();
  #pragma unroll
  for (int p = 0; p < 4; ++p) {
    int nn = ty + p*8;
    Wt[(size_t)(n0+nn)*512 + k0 + tx] = __float2bfloat16(tile[tx][nn]);
  }
}

// ---------------- K1: MFMA GEMM  M=16384, K=512, N=4352 (B^T layout) ----------------
// 256x256 tile, BK=64, 512 threads, 8 waves as 2M x 4N (wave tile 128x64, acc[8][4]).
// Double-buffered LDS (128 KB), XOR-swizzled rows (128 B row = 8 x 16 B slots,
// slot q at row r holds q^(r&7)), stage(t+1) before compute(t), one barrier per K-step.
__global__ __launch_bounds__(512) void k1_mfma(
    const bf16* __restrict__ hb, const bf16* __restrict__ Wt,
    const float* __restrict__ h, const float* __restrict__ predb, const float* __restrict__ writeb,
    bf16* __restrict__ wenc, float* __restrict__ hg, float* __restrict__ errsq)
{
  __shared__ bf16 As[2][256*64];
  __shared__ bf16 Bs[2][256*64];
  const int tid = threadIdx.x;
  const int w = tid >> 6, lane = tid & 63;
  const int n0 = blockIdx.x * 256;     // 0..16
  const int row0 = blockIdx.y * 256;   // 0..63
  const int wm = w & 1, wn = w >> 1;   // 2M x 4N waves of 128x64
  const int mrow = lane & 15, kq = lane >> 4;

  f32x4 acc[8][4];
  #pragma unroll
  for (int i=0;i<8;++i)
    #pragma unroll
    for (int j=0;j<4;++j) acc[i][j] = (f32x4){0.f,0.f,0.f,0.f};

  const int srow  = lane >> 3;                 // row within 8-row group == (tile_row & 7)
  const int sslot = (lane & 7) ^ srow;         // swizzled source slot
  const bf16* gaBase = hb + (size_t)(row0 + w*32 + srow)*512 + sslot*8;
  const bf16* gbBase = Wt + (size_t)(n0  + w*32 + srow)*512 + sslot*8;

  auto STAGE = [&](int buf, int kstep){
    const bf16* ga = gaBase + kstep*64;
    const bf16* gb = gbBase + kstep*64;
    bf16* lA = &As[buf][(w*32)*64];
    bf16* lB = &Bs[buf][(w*32)*64];
    #pragma unroll
    for (int i=0;i<4;++i) {
      GLOAD_LDS16(ga + (size_t)i*8*512, lA + i*8*64);
      GLOAD_LDS16(gb + (size_t)i*8*512, lB + i*8*64);
    }
  };

  auto COMPUTE = [&](int buf){
    #pragma unroll
    for (int kk=0; kk<2; ++kk) {
      bf16x8 bfr[4];
      #pragma unroll
      for (int ni=0;ni<4;++ni) {
        int r = wn*64 + ni*16 + mrow;
        bfr[ni] = *reinterpret_cast<const bf16x8*>(&Bs[buf][r*64 + (((kk*4+kq) ^ (r&7))<<3)]);
      }
      #pragma unroll
      for (int mi=0;mi<8;++mi) {
        int r = wm*128 + mi*16 + mrow;
        bf16x8 af = *reinterpret_cast<const bf16x8*>(&As[buf][r*64 + (((kk*4+kq) ^ (r&7))<<3)]);
        #pragma unroll
        for (int ni=0;ni<4;++ni)
          acc[mi][ni] = __builtin_amdgcn_mfma_f32_16x16x32_bf16(af, bfr[ni], acc[mi][ni], 0, 0, 0);
      }
    }
  };

  STAGE(0, 0);
  __syncthreads();
  #pragma unroll
  for (int t = 0; t < 8; ++t) {
    if (t < 7) STAGE((t+1)&1, t+1);
    COMPUTE(t&1);
    __syncthreads();
  }

  // epilogue: D element (mi,ni,reg) -> row = row0+wm*128+mi*16+kq*4+reg, col = n0+wn*64+ni*16+mrow
  if (n0 < 2048) {
    const int s = n0 >> 9;
    #pragma unroll
    for (int mi=0;mi<8;++mi) {
      #pragma unroll
      for (int reg=0;reg<4;++reg) {
        int r = row0 + wm*128 + mi*16 + kq*4 + reg;
        float sum = 0.f;
        if ((r & 2047) != 2047) {
          #pragma unroll
          for (int ni=0;ni<4;++ni) {
            int o = (n0 & 511) + wn*64 + ni*16 + mrow;
            float P = acc[mi][ni][reg] + predb[s*512 + o];
            float d = P - h[(size_t)(r+1)*512 + o];
            sum = fmaf(d, d, sum);
          }
        }
        #pragma unroll
        for (int off=1; off<16; off<<=1) sum += __shfl_xor(sum, off);
        if (mrow == 0 && (r & 2047) != 2047)
          atomicAdd(&errsq[(size_t)(r+1)*4 + s], sum);
      }
    }
  } else if (n0 < 4096) {
    #pragma unroll
    for (int mi=0;mi<8;++mi)
      #pragma unroll
      for (int ni=0;ni<4;++ni) {
        int n2 = n0 - 2048 + wn*64 + ni*16 + mrow;
        int s = n2 >> 9, o = n2 & 511;
        float wb = writeb[s*512 + o];
        #pragma unroll
        for (int reg=0;reg<4;++reg) {
          int r = row0 + wm*128 + mi*16 + kq*4 + reg;
          wenc[((size_t)r*4 + s)*512 + o] = __float2bfloat16(acc[mi][ni][reg] + wb);
        }
      }
  } else {
    #pragma unroll
    for (int mi=0;mi<8;++mi)
      #pragma unroll
      for (int ni=0;ni<4;++ni) {
        int n2 = wn*64 + ni*16 + mrow;
        int s = n2 >> 6, hh = n2 & 63;
        #pragma unroll
        for (int reg=0;reg<4;++reg) {
          int r = row0 + wm*128 + mi*16 + kq*4 + reg;
          hg[((size_t)r*4 + s)*64 + hh] = acc[mi][ni][reg];
        }
      }
  }
}

// ---------------- K2ab: err = sqrt(errsq+1e-8) (0 at t==0), em = mean_b err ----------------
__global__ void k2ab(const float* __restrict__ errsq, float* __restrict__ err, float* __restrict__ em){
  int i = blockIdx.x*256 + threadIdx.x;   // t*4+s, 8192 total
  int t = i >> 2;
  float sum = 0.f;
  #pragma unroll
  for (int b=0;b<8;++b){
    float e = (t > 0) ? sqrtf(errsq[b*8192 + i] + 1e-8f) : 0.f;
    err[b*8192 + i] = e;
    sum += e;
  }
  em[i] = sum * 0.125f;
}

// ---------------- K2c: EMA scan, chunked-parallel (linear recurrence) ----------------
__global__ __launch_bounds__(256) void k2c_scan(const float* __restrict__ in, float* __restrict__ outv, float init){
  __shared__ float s_in[8192];
  __shared__ float sA[256], sB[256], s_entry[256];
  for (int i = threadIdx.x; i < 8192; i += 256) s_in[i] = in[i];
  __syncthreads();
  const int c = threadIdx.x >> 2, s = threadIdx.x & 3;
  float A = 1.f, B = 0.f;
  #pragma unroll 8
  for (int i = 0; i < 32; ++i) {
    int t = c*32 + i;
    if (t >= 1) { A *= 0.99f; B = fmaf(0.99f, B, 0.01f * s_in[t*4 + s]); }
  }
  sA[threadIdx.x] = A; sB[threadIdx.x] = B;
  __syncthreads();
  if (threadIdx.x < 4) {
    int ss = threadIdx.x;
    float v = init;
    for (int cc = 0; cc < 64; ++cc) {
      s_entry[cc*4 + ss] = v;
      v = fmaf(sA[cc*4 + ss], v, sB[cc*4 + ss]);
    }
  }
  __syncthreads();
  float v = s_entry[threadIdx.x];
  #pragma unroll 8
  for (int i = 0; i < 32; ++i) {
    int t = c*32 + i;
    outv[t*4 + s] = v;
    if (t >= 1) v = fmaf(0.99f, v, 0.01f * s_in[t*4 + s]);
  }
}

// ---------------- K2d: sd[t,s] = mean_b |err - MU| ----------------
__global__ void k2d_sd(const float* __restrict__ err, const float* __restrict__ MU, float* __restrict__ sd){
  int i = blockIdx.x*256 + threadIdx.x;
  float mu = MU[i];
  float sum = 0.f;
  #pragma unroll
  for (int b=0;b<8;++b) sum += fabsf(err[b*8192 + i] - mu);
  sd[i] = sum * 0.125f;
}

// ---------------- K2e: base1[s][k][hh] = gateb1 + semb[k] . gateW1[513:521] ----------------
__global__ void k2e_base(const float* __restrict__ gateW1, const float* __restrict__ semb,
                         const float* __restrict__ gateb1, float* __restrict__ base1){
  int i = blockIdx.x*256 + threadIdx.x;   // (s*3+k)*64+hh, total 768
  if (i < 768) {
    int hh = i & 63, k = (i >> 6) % 3, s = i / 192;
    float acc = gateb1[s*64 + hh];
    #pragma unroll
    for (int e = 0; e < 8; ++e)
      acc = fmaf(semb[k*8+e], gateW1[((size_t)s*521 + 513 + e)*64 + hh], acc);
    base1[i] = acc;
  }
}

// ---------------- K3: one thread per bts computes all 3 gate candidates ----------------
// hg row (256 B) read ONCE; 3 logits accumulated together.
__global__ __launch_bounds__(256) void k3_gall(const float* __restrict__ hg, const float* __restrict__ err,
    const float* __restrict__ MU, const float* __restrict__ SIG,
    const float* __restrict__ gateW1, const float* __restrict__ base1,
    const float* __restrict__ gateW2, const float* __restrict__ gateb2,
    float* __restrict__ g_all)
{
  int bts = blockIdx.x*256 + threadIdx.x;   // 65536
  int s = bts & 3;
  int t = (bts >> 2) & 2047;
  float e = err[bts];
  float z = (e - MU[t*4+s]) / fmaxf(SIG[t*4+s], 1e-3f);
  const float4* hgp  = reinterpret_cast<const float4*>(&hg[(size_t)bts*64]);
  const float4* w1zp = reinterpret_cast<const float4*>(&gateW1[((size_t)s*521 + 512)*64]);
  const float4* w2p  = reinterpret_cast<const float4*>(&gateW2[s*64]);
  const float4* b0p  = reinterpret_cast<const float4*>(&base1[(s*3 + 0)*64]);
  const float4* b1p  = reinterpret_cast<const float4*>(&base1[(s*3 + 1)*64]);
  const float4* b2p  = reinterpret_cast<const float4*>(&base1[(s*3 + 2)*64]);
  float l0 = 0.f, l1 = 0.f, l2 = 0.f;
  #pragma unroll
  for (int hq = 0; hq < 16; ++hq) {
    float4 hv = hgp[hq], wz = w1zp[hq], w2 = w2p[hq];
    float4 b0 = b0p[hq], b1 = b1p[hq], b2 = b2p[hq];
    float cx = fmaf(z, wz.x, hv.x), cy = fmaf(z, wz.y, hv.y);
    float cz = fmaf(z, wz.z, hv.z), cw = fmaf(z, wz.w, hv.w);
    l0 = fmaf(fmaxf(cx + b0.x, 0.f), w2.x, l0);
    l0 = fmaf(fmaxf(cy + b0.y, 0.f), w2.y, l0);
    l0 = fmaf(fmaxf(cz + b0.z, 0.f), w2.z, l0);
    l0 = fmaf(fmaxf(cw + b0.w, 0.f), w2.w, l0);
    l1 = fmaf(fmaxf(cx + b1.x, 0.f), w2.x, l1);
    l1 = fmaf(fmaxf(cy + b1.y, 0.f), w2.y, l1);
    l1 = fmaf(fmaxf(cz + b1.z, 0.f), w2.z, l1);
    l1 = fmaf(fmaxf(cw + b1.w, 0.f), w2.w, l1);
    l2 = fmaf(fmaxf(cx + b2.x, 0.f), w2.x, l2);
    l2 = fmaf(fmaxf(cy + b2.y, 0.f), w2.y, l2);
    l2 = fmaf(fmaxf(cz + b2.z, 0.f), w2.z, l2);
    l2 = fmaf(fmaxf(cw + b2.w, 0.f), w2.w, l2);
  }
  float gb = gateb2[s];
  g_all[(size_t)bts*3 + 0] = 1.f/(1.f + expf(-(l0 + gb)));
  g_all[(size_t)bts*3 + 1] = 1.f/(1.f + expf(-(l1 + gb)));
  g_all[(size_t)bts*3 + 2] = 1.f/(1.f + expf(-(l2 + gb)));
}

// ---------------- K3b: gm[t,s,k] = mean_b g_all ----------------
__global__ void k3b_gm(const float* __restrict__ g_all, float* __restrict__ gm){
  int i = blockIdx.x*256 + threadIdx.x;
  float sum = 0.f;
  #pragma unroll
  for (int b=0;b<8;++b) sum += g_all[((size_t)b*8192 + i/3)*3 + (i%3)];
  gm[i] = sum * 0.125f;
}

// ---------------- K4: state-machine scalar scan (latency-optimized) ----------------
__global__ __launch_bounds__(256) void k4_scan(const float* __restrict__ gm, int* __restrict__ states){
  __shared__ float s_gm[2][6144];
  for (int i = threadIdx.x; i < 6144; i += 256) s_gm[0][i] = gm[i];
  __syncthreads();
  float ema = 0.5f; int st = 0;
  for (int c = 0; c < 4; ++c) {
    if (c < 3)
      for (int i = threadIdx.x; i < 6144; i += 256) s_gm[(c+1)&1][i] = gm[(c+1)*6144 + i];
    if (threadIdx.x < 4) {
      int s = threadIdx.x;
      const float* gp = &s_gm[c&1][s*3];
      int* sp = &states[c*2048 + s];   // states[(c*512+tt)*4+s]
      #pragma unroll 8
      for (int tt = 0; tt < 512; ++tt) {
        sp[tt*4] = st;
        float g0 = gp[tt*12+0], g1 = gp[tt*12+1], g2 = gp[tt*12+2];
        float base = 0.99f * ema;
        float e0 = fmaf(0.01f, g0, base);
        float e1 = fmaf(0.01f, g1, base);
        float e2 = fmaf(0.01f, g2, base);
        ema = (st == 0) ? e0 : ((st == 1) ? e1 : e2);
        int n0 = (ema < 0.1f) ? 1 : 0;
        int n1 = (ema < 0.03f) ? 2 : ((ema > 0.25f) ? 0 : 1);
        int n2 = (ema > 0.25f) ? 0 : 2;
        st = (st == 0) ? n0 : ((st == 1) ? n1 : n2);
      }
    }
    __syncthreads();
  }
}

// ---------------- K6: pass-1 chunk recurrence (av inlined from g_all+states) ----------------
__global__ __launch_bounds__(64) void k6_pass1(const float* __restrict__ g_all, const int* __restrict__ states,
      const bf16* __restrict__ wenc, float* __restrict__ q, float* __restrict__ Pc){
  int c = blockIdx.x, s = blockIdx.y, b = blockIdx.z;
  int d0 = threadIdx.x * 4;          // dims [d0,d0+4) and [256+d0, 256+d0+4)
  __shared__ float s_a[CH];
  if (threadIdx.x < CH) {
    int t = c*CH + threadIdx.x;
    int st = states[t*4 + s];
    float gain = (st == 0) ? 1.f : ((st == 1) ? 0.5f : 0.1f);
    s_a[threadIdx.x] = g_all[((size_t)(b*2048 + t)*4 + s)*3 + st] * gain;
  }
  __syncthreads();
  float qv[8];
  #pragma unroll
  for (int j=0;j<8;++j) qv[j] = 0.f;
  float p = 1.f;
  const bf16* wp = &wenc[((size_t)(b*2048 + c*CH)*4 + s)*512];
  #pragma unroll 4
  for (int i = 0; i < CH; ++i) {
    float av = s_a[i];
    float om = 1.f - av;
    bf16x4 w1 = *reinterpret_cast<const bf16x4*>(wp + (size_t)i*2048 + d0);
    bf16x4 w2 = *reinterpret_cast<const bf16x4*>(wp + (size_t)i*2048 + 256 + d0);
    #pragma unroll
    for (int j=0;j<4;++j) qv[j]   = fmaf(om, qv[j],   av*b2fs(w1[j]));
    #pragma unroll
    for (int j=0;j<4;++j) qv[4+j] = fmaf(om, qv[4+j], av*b2fs(w2[j]));
    p *= om;
  }
  float* qp = &q[((size_t)(b*4+s)*NCHUNK + c)*512];
  *reinterpret_cast<float4*>(qp + d0)       = make_float4(qv[0],qv[1],qv[2],qv[3]);
  *reinterpret_cast<float4*>(qp + 256 + d0) = make_float4(qv[4],qv[5],qv[6],qv[7]);
  if (threadIdx.x == 0) Pc[(b*4+s)*NCHUNK + c] = p;
}

// ---------------- K7: boundary scan (float4) ----------------
__global__ __launch_bounds__(128) void k7_bound(const float* __restrict__ q, const float* __restrict__ Pc,
      const float* __restrict__ w0, float* __restrict__ m_start){
  int s = blockIdx.x, b = blockIdx.y, d4 = threadIdx.x * 4;
  float4 m = *reinterpret_cast<const float4*>(&w0[s*512 + d4]);
  for (int c = 0; c < NCHUNK; ++c) {
    *reinterpret_cast<float4*>(&m_start[((size_t)(b*4+s)*NCHUNK + c)*512 + d4]) = m;
    float pc = Pc[(b*4+s)*NCHUNK + c];
    float4 qv = *reinterpret_cast<const float4*>(&q[((size_t)(b*4+s)*NCHUNK + c)*512 + d4]);
    m.x = fmaf(pc, m.x, qv.x);
    m.y = fmaf(pc, m.y, qv.y);
    m.z = fmaf(pc, m.z, qv.z);
    m.w = fmaf(pc, m.w, qv.w);
  }
}

// ---------------- K8: pass-2 emit (av inlined from g_all+states) ----------------
__global__ __launch_bounds__(64) void k8_pass2(const float* __restrict__ g_all, const int* __restrict__ states,
      const bf16* __restrict__ wenc, const float* __restrict__ m_start, float* __restrict__ out){
  int c = blockIdx.x, s = blockIdx.y, b = blockIdx.z;
  int d0 = threadIdx.x * 4;
  __shared__ float s_a[CH];
  if (threadIdx.x < CH) {
    int t = c*CH + threadIdx.x;
    int st = states[t*4 + s];
    float gain = (st == 0) ? 1.f : ((st == 1) ? 0.5f : 0.1f);
    s_a[threadIdx.x] = g_all[((size_t)(b*2048 + t)*4 + s)*3 + st] * gain;
  }
  __syncthreads();
  const float* msp = &m_start[((size_t)(b*4+s)*NCHUNK + c)*512];
  float4 m1 = *reinterpret_cast<const float4*>(msp + d0);
  float4 m2 = *reinterpret_cast<const float4*>(msp + 256 + d0);
  const bf16* wp = &wenc[((size_t)(b*2048 + c*CH)*4 + s)*512];
  float* op = &out[((size_t)(b*2048 + c*CH))*2048 + s*512];
  #pragma unroll 2
  for (int i = 0; i < CH; ++i) {
    float av = s_a[i];
    float om = 1.f - av;
    bf16x4 w1 = *reinterpret_cast<const bf16x4*>(wp + (size_t)i*2048 + d0);
    bf16x4 w2 = *reinterpret_cast<const bf16x4*>(wp + (size_t)i*2048 + 256 + d0);
    m1.x = fmaf(om, m1.x, av*b2fs(w1[0]));
    m1.y = fmaf(om, m1.y, av*b2fs(w1[1]));
    m1.z = fmaf(om, m1.z, av*b2fs(w1[2]));
    m1.w = fmaf(om, m1.w, av*b2fs(w1[3]));
    m2.x = fmaf(om, m2.x, av*b2fs(w2[0]));
    m2.y = fmaf(om, m2.y, av*b2fs(w2[1]));
    m2.z = fmaf(om, m2.z, av*b2fs(w2[2]));
    m2.w = fmaf(om, m2.w, av*b2fs(w2[3]));
    *reinterpret_cast<float4*>(op + (size_t)i*2048 + d0)       = m1;
    *reinterpret_cast<float4*>(op + (size_t)i*2048 + 256 + d0) = m2;
  }
}

extern "C" void kernel_launch(void* const* d_in, const int* in_sizes, int n_in,
                              void* d_out, int out_size, void* d_ws, size_t ws_size,
                              hipStream_t stream) {
  (void)in_sizes; (void)n_in; (void)out_size; (void)ws_size;
  const float* h      = (const float*)d_in[0];
  const float* predW  = (const float*)d_in[1];
  const float* predb  = (const float*)d_in[2];
  const float* gateW1 = (const float*)d_in[3];
  const float* gateb1 = (const float*)d_in[4];
  const float* gateW2 = (const float*)d_in[5];
  const float* gateb2 = (const float*)d_in[6];
  const float* writeW = (const float*)d_in[7];
  const float* writeb = (const float*)d_in[8];
  const float* w0     = (const float*)d_in[9];
  const float* semb   = (const float*)d_in[10];
  float* out = (float*)d_out;

  char* ws = (char*)d_ws;
  size_t off = 0;
  auto alloc = [&](size_t bytes) -> char* {
    char* p = ws + off; off += (bytes + 255) / 256 * 256; return p;
  };
  bf16*  wenc   = (bf16*) alloc((size_t)Bb*Tt*Ss*Dd*2);      // 67 MB
  float* hg     = (float*)alloc((size_t)Bb*Tt*Ss*GHh*4);     // 16.8 MB
  bf16*  hb     = (bf16*) alloc((size_t)Bb*Tt*Dd*2);         // 16.8 MB
  bf16*  Wt     = (bf16*) alloc((size_t)4352*512*2);         // 4.5 MB
  float* errsq  = (float*)alloc((size_t)Bb*Tt*Ss*4);
  float* err    = (float*)alloc((size_t)Bb*Tt*Ss*4);
  float* em     = (float*)alloc((size_t)Tt*Ss*4);
  float* MU     = (float*)alloc((size_t)Tt*Ss*4);
  float* sd     = (float*)alloc((size_t)Tt*Ss*4);
  float* SIG    = (float*)alloc((size_t)Tt*Ss*4);
  float* base1  = (float*)alloc((size_t)Ss*3*GHh*4);
  float* g_all  = (float*)alloc((size_t)Bb*Tt*Ss*3*4);       // 3 MB
  float* gm     = (float*)alloc((size_t)Tt*Ss*3*4);
  int*   states = (int*)  alloc((size_t)Tt*Ss*4);
  float* Pc     = (float*)alloc((size_t)Bb*Ss*NCHUNK*4);
  float* q      = (float*)alloc((size_t)Bb*Ss*NCHUNK*Dd*4);  // 4 MB
  float* mst    = (float*)alloc((size_t)Bb*Ss*NCHUNK*Dd*4);  // 4 MB

  hipMemsetAsync(errsq, 0, (size_t)Bb*Tt*Ss*4, stream);

  k0a_cvt<<<(Bb*Tt*Dd)/(256*4), 256, 0, stream>>>(h, hb);
  dim3 g0b(16, 136);
  k0b_pack<<<g0b, 256, 0, stream>>>(predW, writeW, gateW1, Wt);
  dim3 g1(17, 64);
  k1_mfma<<<g1, 512, 0, stream>>>(hb, Wt, h, predb, writeb, wenc, hg, errsq);
  k2ab<<<(Tt*Ss)/256, 256, 0, stream>>>(errsq, err, em);
  k2c_scan<<<1, 256, 0, stream>>>(em, MU, 0.f);
  k2d_sd<<<(Tt*Ss)/256, 256, 0, stream>>>(err, MU, sd);
  k2c_scan<<<1, 256, 0, stream>>>(sd, SIG, 1.f);
  k2e_base<<<3, 256, 0, stream>>>(gateW1, semb, gateb1, base1);
  k3_gall<<<(Bb*Tt*Ss)/256, 256, 0, stream>>>(hg, err, MU, SIG, gateW1, base1, gateW2, gateb2, g_all);
  k3b_gm<<<(Tt*Ss*3)/256, 256, 0, stream>>>(g_all, gm);
  k4_scan<<<1, 256, 0, stream>>>(gm, states);
  dim3 g6(NCHUNK, Ss, Bb);
  k6_pass1<<<g6, 64, 0, stream>>>(g_all, states, wenc, q, Pc);
  dim3 g7(Ss, Bb);
  k7_bound<<<g7, 128, 0, stream>>>(q, Pc, w0, mst);
  k8_pass2<<<g6, 64, 0, stream>>>(g_all, states, wenc, mst, out);
}